// Round 4
// baseline (676.578 us; speedup 1.0000x reference)
//
#include <hip/hip_runtime.h>
#include <hip/hip_bf16.h>

// BasicCae: x[256,28224] fp32, W_enc[1500,28224], b_enc[1500], W_dec[28224,1500], b_dec[28224]
// out: y_out[256,28224] fp32 ++ jac_reg scalar (at index 7225344)
//
// R8: no-LDS no-barrier streaming GEMMs.
// Post-mortem R6/R7: LDS staging + per-iter barrier drain (vmcnt(0) before
// s_barrier) is the structural bottleneck; A has no cross-wave reuse inside a
// block (waves own disjoint M rows), B re-reads are L2-hits. So each wave
// streams K independently: A-frags via direct per-lane global loads (16 lines
// x 64B per instr, L2/L3-served), B fp32 loaded + pack2-converted in-reg,
// 1-iter software prefetch with even/odd frag sets (no runtime-indexed
// arrays -> no scratch). Zero LDS, zero barriers in the GEMMs.

#define BATCH 256
#define IN    28224
#define FEAT  1500
#define FPAD  1536   /* enc N padding & partial stride */
#define KPAD  1504   /* dec K padding (1500 -> 47*32)  */
#define ENC_S 42     /* enc split-K factor; kchunk = 672 = 21*32 */

typedef __attribute__((ext_vector_type(8))) short short8;   // 8 bf16
typedef __attribute__((ext_vector_type(4))) float f32x4;    // MFMA acc

__device__ __forceinline__ unsigned pack2(float lo, float hi) {
    unsigned a = __float_as_uint(lo) + 0x8000u;
    unsigned b = __float_as_uint(hi) + 0x8000u;
    return __builtin_amdgcn_perm(b, a, 0x07060302);  // (hi16(b)<<16)|hi16(a)
}
__device__ __forceinline__ unsigned short f2bf(float f) {
    unsigned u = __float_as_uint(f);
    return (unsigned short)((u + 0x7FFFu + ((u >> 16) & 1u)) >> 16);
}
__device__ __forceinline__ short8 packs8(float4 lo, float4 hi) {
    union { unsigned u[4]; short8 s; } U;
    U.u[0] = pack2(lo.x, lo.y);
    U.u[1] = pack2(lo.z, lo.w);
    U.u[2] = pack2(hi.x, hi.y);
    U.u[3] = pack2(hi.z, hi.w);
    return U.s;
}

// ================= streaming converts =================

__global__ __launch_bounds__(256) void cvt_x(const float* __restrict__ x,
                                             unsigned short* __restrict__ xbf) {
    int idx = blockIdx.x * 256 + threadIdx.x;       // 7056*256 float4s
    float4 v = ((const float4*)x)[idx];
    ((uint2*)xbf)[idx] = make_uint2(pack2(v.x, v.y), pack2(v.z, v.w));
}

// ================= R8 streaming GEMMs =================
// Fragment layout (same as R6/R7, verified): lane(l15,quad) of a wave holds
// row (tilebase + l15), k-slice quad*8..quad*8+7 for both A and B operands.

struct EncFrag { short8 a0, a1, a2, a3, b0, b1, b2, b3; };
struct EncStage { float4 p0, p1, p2, p3, p4, p5, p6, p7; };

__device__ __forceinline__ void enc_loadA(EncFrag& F, const unsigned short* A0, int k) {
    F.a0 = *(const short8*)(A0 + k);
    F.a1 = *(const short8*)(A0 + 16 * IN + k);
    F.a2 = *(const short8*)(A0 + 32 * IN + k);
    F.a3 = *(const short8*)(A0 + 48 * IN + k);
}
__device__ __forceinline__ void enc_loadB(EncStage& S, const float* b0, const float* b1,
                                          const float* b2, const float* b3, int k) {
    S.p0 = *(const float4*)(b0 + k); S.p1 = *(const float4*)(b0 + k + 4);
    S.p2 = *(const float4*)(b1 + k); S.p3 = *(const float4*)(b1 + k + 4);
    S.p4 = *(const float4*)(b2 + k); S.p5 = *(const float4*)(b2 + k + 4);
    S.p6 = *(const float4*)(b3 + k); S.p7 = *(const float4*)(b3 + k + 4);
}
__device__ __forceinline__ float dot8(float4 a, float4 b) {
    return a.x*a.x + a.y*a.y + a.z*a.z + a.w*a.w
         + b.x*b.x + b.y*b.y + b.z*b.z + b.w*b.w;
}
__device__ __forceinline__ void enc_cvtB(EncFrag& F, const EncStage& S, bool dosq,
                                         float& r0, float& r1, float& r2, float& r3) {
    F.b0 = packs8(S.p0, S.p1);
    F.b1 = packs8(S.p2, S.p3);
    F.b2 = packs8(S.p4, S.p5);
    F.b3 = packs8(S.p6, S.p7);
    if (dosq) {
        r0 += dot8(S.p0, S.p1);
        r1 += dot8(S.p2, S.p3);
        r2 += dot8(S.p4, S.p5);
        r3 += dot8(S.p6, S.p7);
    }
}
__device__ __forceinline__ void enc_mfma(f32x4 (&acc)[4][4], const EncFrag& F) {
    short8 A[4] = {F.a0, F.a1, F.a2, F.a3};
    short8 B[4] = {F.b0, F.b1, F.b2, F.b3};
#pragma unroll
    for (int mt = 0; mt < 4; ++mt)
#pragma unroll
        for (int nt = 0; nt < 4; ++nt)
            acc[mt][nt] = __builtin_amdgcn_mfma_f32_16x16x32_bf16(A[mt], B[nt], acc[mt][nt], 0, 0, 0);
}

// Encoder: part[s] = xbf[256 rows] . We^T[64 cols, fp32] over K-chunk s.
// Block: 4 waves, wave-tile 64M x 64N, 21 K-iters of 32. No LDS, no barriers.
__global__ __launch_bounds__(256) void enc_stream(const unsigned short* __restrict__ xbf,
                                                  const float* __restrict__ We,
                                                  float* __restrict__ part,
                                                  float* __restrict__ rn2) {
    const int n0 = blockIdx.x * 64;                  // feature base (24 tiles -> 1536)
    const int kb = blockIdx.y * 672;                 // split-K chunk (21 iters)
    const int t    = threadIdx.x;
    const int lane = t & 63;
    const int w    = t >> 6;
    const int l15  = lane & 15;
    const int quad = lane >> 4;

    // A: per-lane direct; base row = w*64 + l15 (mt adds 16 rows)
    const unsigned short* A0 = xbf + (long)(w * 64 + l15) * IN + kb + quad * 8;

    // B rows (clamped; garbage lands in part cols >= FEAT which are never read)
    const int rb0 = n0 + 0  + l15, rb1 = n0 + 16 + l15;
    const int rb2 = n0 + 32 + l15, rb3 = n0 + 48 + l15;
    const float* b0p = We + (long)(rb0 < FEAT ? rb0 : FEAT - 1) * IN + kb + quad * 8;
    const float* b1p = We + (long)(rb1 < FEAT ? rb1 : FEAT - 1) * IN + kb + quad * 8;
    const float* b2p = We + (long)(rb2 < FEAT ? rb2 : FEAT - 1) * IN + kb + quad * 8;
    const float* b3p = We + (long)(rb3 < FEAT ? rb3 : FEAT - 1) * IN + kb + quad * 8;

    const bool dosq = (w == 0);                      // rn2 counted once per block
    float r0 = 0.f, r1 = 0.f, r2 = 0.f, r3 = 0.f;

    f32x4 acc[4][4];
#pragma unroll
    for (int mt = 0; mt < 4; ++mt)
#pragma unroll
        for (int nt = 0; nt < 4; ++nt) { f32x4 z = {0.f,0.f,0.f,0.f}; acc[mt][nt] = z; }

    EncFrag F0, F1; EncStage S;
    enc_loadA(F0, A0, 0);
    enc_loadB(S, b0p, b1p, b2p, b3p, 0);
    enc_cvtB(F0, S, dosq, r0, r1, r2, r3);

#pragma unroll 1
    for (int p = 0; p < 10; ++p) {                   // pairs: computes iters 0..19, loads 1..20
        const int k1 = (2 * p + 1) * 32;
        const int k2 = (2 * p + 2) * 32;
        enc_loadA(F1, A0, k1);
        enc_loadB(S, b0p, b1p, b2p, b3p, k1);
        enc_mfma(acc, F0);                           // overlaps k1 loads
        enc_cvtB(F1, S, dosq, r0, r1, r2, r3);
        enc_loadA(F0, A0, k2);
        enc_loadB(S, b0p, b1p, b2p, b3p, k2);
        enc_mfma(acc, F1);                           // overlaps k2 loads
        enc_cvtB(F0, S, dosq, r0, r1, r2, r3);
    }
    enc_mfma(acc, F0);                               // iter 20

    float* ps = part + (long)blockIdx.y * (BATCH * FPAD);
#pragma unroll
    for (int nt = 0; nt < 4; ++nt) {
        const int col = n0 + nt * 16 + l15;          // < 1536, padded, no guard
#pragma unroll
        for (int mt = 0; mt < 4; ++mt) {
            const int row = w * 64 + mt * 16 + quad * 4;
#pragma unroll
            for (int r = 0; r < 4; ++r)
                ps[(long)(row + r) * FPAD + col] = acc[mt][nt][r];
        }
    }

    // rn2: sum r_nt over the 4 quads (lanes sharing l15), then one atomic per row
    r0 += __shfl_xor(r0, 16); r0 += __shfl_xor(r0, 32);
    r1 += __shfl_xor(r1, 16); r1 += __shfl_xor(r1, 32);
    r2 += __shfl_xor(r2, 16); r2 += __shfl_xor(r2, 32);
    r3 += __shfl_xor(r3, 16); r3 += __shfl_xor(r3, 32);
    if (dosq && lane < 16) {
        if (rb0 < FEAT) atomicAdd(&rn2[rb0], r0);
        if (rb1 < FEAT) atomicAdd(&rn2[rb1], r1);
        if (rb2 < FEAT) atomicAdd(&rn2[rb2], r2);
        if (rb3 < FEAT) atomicAdd(&rn2[rb3], r3);
    }
}

// Reduce ENC_S fp32 partials + bias -> sigmoid -> yenc bf16 [256][1504] + jac.
__global__ __launch_bounds__(256) void act_jac_f(const float* __restrict__ part,
                                                 const float* __restrict__ be,
                                                 const float* __restrict__ rn2,
                                                 unsigned short* __restrict__ yenc,
                                                 float* __restrict__ jac) {
    const int b = blockIdx.y;
    const int f = blockIdx.x * 256 + threadIdx.x;   // 0..1535
    float local = 0.0f;
    unsigned short h = 0;
    if (f < FEAT) {
        float p = be[f];
#pragma unroll 6
        for (int s = 0; s < ENC_S; ++s)
            p += part[(long)(s * BATCH + b) * FPAD + f];
        float y = 1.0f / (1.0f + __expf(-p));
        h = f2bf(y);
        float sg = y * (1.0f - y);
        local = sg * sg * rn2[f];
    }
    if (f < KPAD) yenc[b * KPAD + f] = h;           // zeros for 1500..1503

    float v = local;
#pragma unroll
    for (int off = 32; off > 0; off >>= 1) v += __shfl_down(v, off);
    __shared__ float red[4];
    if ((threadIdx.x & 63) == 0) red[threadIdx.x >> 6] = v;
    __syncthreads();
    if (threadIdx.x == 0) atomicAdd(jac, red[0] + red[1] + red[2] + red[3]);
}

// Decoder: out = sigmoid(yenc[256 rows, bf16] . Wd^T[32 cols, fp32] + b_dec); K=1504.
// Block: 4 waves, wave-tile 64M x 32N, 47 K-iters of 32. No LDS, no barriers.
struct DecFrag { short8 a0, a1, a2, a3, b0, b1; };
struct DecStage { float4 p0, p1, p2, p3; };

__device__ __forceinline__ void dec_loadA(DecFrag& F, const unsigned short* A0, int k) {
    F.a0 = *(const short8*)(A0 + k);
    F.a1 = *(const short8*)(A0 + 16 * KPAD + k);
    F.a2 = *(const short8*)(A0 + 32 * KPAD + k);
    F.a3 = *(const short8*)(A0 + 48 * KPAD + k);
}
__device__ __forceinline__ void dec_loadB(DecStage& S, const float* b0, const float* b1,
                                          const float* WdEnd, int k) {
    // lo float4 (cols c..c+3, c<=1496) is always within the row/array;
    // hi float4 can cross the array end only for row 28223, last iter -> clamp.
    S.p0 = *(const float4*)(b0 + k);
    const float* q0 = b0 + k + 4;
    if (q0 + 4 > WdEnd) q0 = WdEnd - 4;             // value irrelevant: A pad cols are 0
    S.p1 = *(const float4*)q0;
    S.p2 = *(const float4*)(b1 + k);
    const float* q1 = b1 + k + 4;
    if (q1 + 4 > WdEnd) q1 = WdEnd - 4;
    S.p3 = *(const float4*)q1;
}
__device__ __forceinline__ void dec_cvtB(DecFrag& F, const DecStage& S) {
    F.b0 = packs8(S.p0, S.p1);
    F.b1 = packs8(S.p2, S.p3);
}
__device__ __forceinline__ void dec_mfma(f32x4 (&acc)[4][2], const DecFrag& F) {
    short8 A[4] = {F.a0, F.a1, F.a2, F.a3};
    short8 B[2] = {F.b0, F.b1};
#pragma unroll
    for (int mt = 0; mt < 4; ++mt)
#pragma unroll
        for (int nt = 0; nt < 2; ++nt)
            acc[mt][nt] = __builtin_amdgcn_mfma_f32_16x16x32_bf16(A[mt], B[nt], acc[mt][nt], 0, 0, 0);
}

__global__ __launch_bounds__(256) void dec_stream(const unsigned short* __restrict__ yenc,
                                                  const float* __restrict__ Wd,
                                                  const float* __restrict__ bd,
                                                  float* __restrict__ out) {
    const int n0 = blockIdx.x * 32;                  // 882 tiles * 32 = 28224 exact
    const int t    = threadIdx.x;
    const int lane = t & 63;
    const int w    = t >> 6;
    const int l15  = lane & 15;
    const int quad = lane >> 4;

    const unsigned short* A0 = yenc + (long)(w * 64 + l15) * KPAD + quad * 8;

    const int rb0 = n0 + l15, rb1 = n0 + 16 + l15;   // < 28224 always
    const float* b0p = Wd + (long)rb0 * FEAT + quad * 8;
    const float* b1p = Wd + (long)rb1 * FEAT + quad * 8;
    const float* WdEnd = Wd + (long)IN * FEAT;       // array end

    f32x4 acc[4][2];
#pragma unroll
    for (int mt = 0; mt < 4; ++mt)
#pragma unroll
        for (int nt = 0; nt < 2; ++nt) { f32x4 z = {0.f,0.f,0.f,0.f}; acc[mt][nt] = z; }

    DecFrag F0, F1; DecStage S;
    dec_loadA(F0, A0, 0);
    dec_loadB(S, b0p, b1p, WdEnd, 0);
    dec_cvtB(F0, S);

#pragma unroll 1
    for (int p = 0; p < 23; ++p) {                   // computes iters 0..45, loads 1..46
        const int k1 = (2 * p + 1) * 32;
        const int k2 = (2 * p + 2) * 32;
        dec_loadA(F1, A0, k1);
        dec_loadB(S, b0p, b1p, WdEnd, k1);
        dec_mfma(acc, F0);
        dec_cvtB(F1, S);
        dec_loadA(F0, A0, k2);
        dec_loadB(S, b0p, b1p, WdEnd, k2);
        dec_mfma(acc, F1);
        dec_cvtB(F0, S);
    }
    dec_mfma(acc, F0);                               // iter 46

#pragma unroll
    for (int nt = 0; nt < 2; ++nt) {
        const int col = n0 + nt * 16 + l15;
        const float bias = bd[col];
#pragma unroll
        for (int mt = 0; mt < 4; ++mt) {
            const int row = w * 64 + mt * 16 + quad * 4;
#pragma unroll
            for (int r = 0; r < 4; ++r) {
                float v = acc[mt][nt][r] + bias;
                out[(long)(row + r) * IN + col] = 1.0f / (1.0f + __expf(-v));
            }
        }
    }
}

// ================= R4 fallback path (proven; used if ws too small) =================
#define LDA 40

__global__ __launch_bounds__(256) void enc_gemm(const unsigned short* __restrict__ xbf,
                                                const float* __restrict__ We,
                                                float* __restrict__ preact,
                                                float* __restrict__ rn2) {
    __shared__ unsigned short As[256 * LDA];
    __shared__ unsigned short Bs[64 * LDA];
    const int n0 = blockIdx.x * 64;
    const int kb = blockIdx.y * 672;
    const int t = threadIdx.x, lane = t & 63, w = t >> 6, l15 = lane & 15, quad = lane >> 4;
    const unsigned short* asrc = xbf + (long)(t >> 2) * IN + (t & 3) * 8 + kb;
    unsigned short* adst = As + (t >> 2) * LDA + (t & 3) * 8;
    const int brow = t >> 3, bc4 = t & 7;
    const int f0 = n0 + brow, f1 = f0 + 32;
    const float* bsrc0 = We + (long)(f0 < FEAT ? f0 : FEAT - 1) * IN + bc4 * 4 + kb;
    const float* bsrc1 = We + (long)(f1 < FEAT ? f1 : FEAT - 1) * IN + bc4 * 4 + kb;
    unsigned short* bdst0 = Bs + brow * LDA + bc4 * 4;
    unsigned short* bdst1 = bdst0 + 32 * LDA;
    float rsq0 = 0.f, rsq1 = 0.f;
    f32x4 acc[4][4];
#pragma unroll
    for (int mt = 0; mt < 4; ++mt)
#pragma unroll
        for (int nt = 0; nt < 4; ++nt) { f32x4 z = {0.f,0.f,0.f,0.f}; acc[mt][nt] = z; }
    for (int k = 0; k < 672; k += 32) {
        short8 av[4];
#pragma unroll
        for (int j = 0; j < 4; ++j) av[j] = *(const short8*)(asrc + (long)64 * j * IN + k);
        const float4 bv0 = *(const float4*)(bsrc0 + k);
        const float4 bv1 = *(const float4*)(bsrc1 + k);
        __syncthreads();
#pragma unroll
        for (int j = 0; j < 4; ++j) *(short8*)(adst + 64 * j * LDA) = av[j];
        *(uint2*)bdst0 = make_uint2(pack2(bv0.x, bv0.y), pack2(bv0.z, bv0.w));
        *(uint2*)bdst1 = make_uint2(pack2(bv1.x, bv1.y), pack2(bv1.z, bv1.w));
        rsq0 += bv0.x*bv0.x + bv0.y*bv0.y + bv0.z*bv0.z + bv0.w*bv0.w;
        rsq1 += bv1.x*bv1.x + bv1.y*bv1.y + bv1.z*bv1.z + bv1.w*bv1.w;
        __syncthreads();
        short8 a[4], b[4];
#pragma unroll
        for (int mt = 0; mt < 4; ++mt) a[mt] = *(const short8*)(As + (w * 64 + mt * 16 + l15) * LDA + quad * 8);
#pragma unroll
        for (int nt = 0; nt < 4; ++nt) b[nt] = *(const short8*)(Bs + (nt * 16 + l15) * LDA + quad * 8);
#pragma unroll
        for (int mt = 0; mt < 4; ++mt)
#pragma unroll
            for (int nt = 0; nt < 4; ++nt)
                acc[mt][nt] = __builtin_amdgcn_mfma_f32_16x16x32_bf16(a[mt], b[nt], acc[mt][nt], 0, 0, 0);
    }
#pragma unroll
    for (int nt = 0; nt < 4; ++nt) {
        const int col = n0 + nt * 16 + l15;
        if (col < FEAT) {
#pragma unroll
            for (int mt = 0; mt < 4; ++mt) {
                float* p = preact + (long)(w * 64 + mt * 16 + quad * 4) * FEAT + col;
#pragma unroll
                for (int r = 0; r < 4; ++r) atomicAdd(p + (long)r * FEAT, acc[mt][nt][r]);
            }
        }
    }
    {
        float v0 = rsq0, v1 = rsq1;
#pragma unroll
        for (int off = 1; off < 8; off <<= 1) { v0 += __shfl_xor(v0, off); v1 += __shfl_xor(v1, off); }
        if ((lane & 7) == 0) {
            if (f0 < FEAT) atomicAdd(&rn2[f0], v0);
            if (f1 < FEAT) atomicAdd(&rn2[f1], v1);
        }
    }
}

__global__ __launch_bounds__(256) void act_jac(const float* __restrict__ preact,
                                               const float* __restrict__ be,
                                               const float* __restrict__ rn2,
                                               unsigned short* __restrict__ yenc,
                                               float* __restrict__ jac) {
    const int b = blockIdx.y;
    const int f = blockIdx.x * 256 + threadIdx.x;
    float local = 0.0f;
    unsigned short h = 0;
    if (f < FEAT) {
        float p = preact[b * FEAT + f] + be[f];
        float y = 1.0f / (1.0f + __expf(-p));
        h = f2bf(y);
        float s = y * (1.0f - y);
        local = s * s * rn2[f];
    }
    yenc[b * FPAD + f] = h;
    float v = local;
#pragma unroll
    for (int off = 32; off > 0; off >>= 1) v += __shfl_down(v, off);
    __shared__ float red[4];
    if ((threadIdx.x & 63) == 0) red[threadIdx.x >> 6] = v;
    __syncthreads();
    if (threadIdx.x == 0) atomicAdd(jac, red[0] + red[1] + red[2] + red[3]);
}

__global__ __launch_bounds__(256) void dec_gemm(const unsigned short* __restrict__ yenc,
                                                const float* __restrict__ Wd,
                                                const float* __restrict__ bd,
                                                float* __restrict__ out) {
    __shared__ unsigned short As[128 * LDA];
    __shared__ unsigned short Bs[64 * LDA];
    const int m0 = (blockIdx.x & 1) * 128;
    const int n0 = (blockIdx.x >> 1) * 64;
    const int t = threadIdx.x, lane = t & 63, w = t >> 6, l15 = lane & 15, quad = lane >> 4;
    const int mrow = (w >> 1) * 64, ncol = (w & 1) * 32;
    const unsigned short* asrc = yenc + (long)(m0 + (t >> 2)) * FPAD + (t & 3) * 8;
    unsigned short* adst = As + (t >> 2) * LDA + (t & 3) * 8;
    const float* bsrc = Wd + (long)(n0 + (t >> 3)) * FEAT + (t & 7) * 4;
    unsigned short* bdst = Bs + (t >> 3) * LDA + (t & 7) * 4;
    f32x4 acc[4][2];
#pragma unroll
    for (int mt = 0; mt < 4; ++mt)
#pragma unroll
        for (int nt = 0; nt < 2; ++nt) { f32x4 z = {0.f,0.f,0.f,0.f}; acc[mt][nt] = z; }
    for (int k = 0; k < 1504; k += 32) {
        short8 av[2];
#pragma unroll
        for (int j = 0; j < 2; ++j) av[j] = *(const short8*)(asrc + (long)64 * j * FPAD + k);
        float4 bv0, bv1;
        if (k < 1472) {
            bv0 = *(const float4*)(bsrc + k);
            bv1 = *(const float4*)(bsrc + (long)32 * FEAT + k);
        } else {
            if ((t & 7) == 7) { bv0 = make_float4(0,0,0,0); bv1 = bv0; }
            else {
                bv0 = *(const float4*)(bsrc + k);
                bv1 = *(const float4*)(bsrc + (long)32 * FEAT + k);
            }
        }
        __syncthreads();
#pragma unroll
        for (int j = 0; j < 2; ++j) *(short8*)(adst + 64 * j * LDA) = av[j];
        *(uint2*)bdst = make_uint2(pack2(bv0.x, bv0.y), pack2(bv0.z, bv0.w));
        *(uint2*)(bdst + 32 * LDA) = make_uint2(pack2(bv1.x, bv1.y), pack2(bv1.z, bv1.w));
        __syncthreads();
        short8 a[4], b[2];
#pragma unroll
        for (int mt = 0; mt < 4; ++mt) a[mt] = *(const short8*)(As + (mrow + mt * 16 + l15) * LDA + quad * 8);
#pragma unroll
        for (int nt = 0; nt < 2; ++nt) b[nt] = *(const short8*)(Bs + (ncol + nt * 16 + l15) * LDA + quad * 8);
#pragma unroll
        for (int mt = 0; mt < 4; ++mt)
#pragma unroll
            for (int nt = 0; nt < 2; ++nt)
                acc[mt][nt] = __builtin_amdgcn_mfma_f32_16x16x32_bf16(a[mt], b[nt], acc[mt][nt], 0, 0, 0);
    }
#pragma unroll
    for (int nt = 0; nt < 2; ++nt) {
        const int col = n0 + ncol + nt * 16 + l15;
        const float bias = bd[col];
#pragma unroll
        for (int mt = 0; mt < 4; ++mt) {
            const int row = m0 + mrow + mt * 16 + quad * 4;
#pragma unroll
            for (int r = 0; r < 4; ++r) {
                float v = acc[mt][nt][r] + bias;
                out[(long)(row + r) * IN + col] = 1.0f / (1.0f + __expf(-v));
            }
        }
    }
}

// ================= launch =================
extern "C" void kernel_launch(void* const* d_in, const int* in_sizes, int n_in,
                              void* d_out, int out_size, void* d_ws, size_t ws_size,
                              hipStream_t stream) {
    const float* x  = (const float*)d_in[0];
    const float* We = (const float*)d_in[1];
    const float* be = (const float*)d_in[2];
    const float* Wd = (const float*)d_in[3];
    const float* bd = (const float*)d_in[4];
    float* out = (float*)d_out;
    char* ws = (char*)d_ws;

    // Fast-path ws layout (16B-aligned), total 81,287,168 B:
    //   xbf   bf16 [256][28224]    @ 0           (14,450,688)
    //   yenc  bf16 [256][1504]     @ 14,450,688  (   770,048)
    //   part  fp32 [42][256][1536] @ 15,220,736  (66,060,288)
    //   rn2   fp32 [1536]          @ 81,281,024  (     6,144)
    if (ws_size >= 81287168ull) {
        unsigned short* xbf  = (unsigned short*)ws;
        unsigned short* yenc = (unsigned short*)(ws + 14450688);
        float* part          = (float*)(ws + 15220736);
        float* rn2           = (float*)(ws + 81281024);

        hipMemsetAsync(rn2, 0, 6144, stream);
        hipMemsetAsync(out + 7225344, 0, 4, stream);        // jac slot

        cvt_x<<<7056, 256, 0, stream>>>(x, xbf);
        enc_stream<<<dim3(24, ENC_S), 256, 0, stream>>>(xbf, We, part, rn2);
        act_jac_f<<<dim3(6, 256), 256, 0, stream>>>(part, be, rn2, yenc, out + 7225344);
        dec_stream<<<882, 256, 0, stream>>>(yenc, Wd, bd, out);
    } else {
        // R4 fallback: preact fp32 @0 (1,536,000) | rn2 @1,536,000 | yenc @1,542,144 | xbf @2,328,576
        float* preact        = (float*)ws;
        float* rn2           = (float*)(ws + 1536000);
        unsigned short* yenc = (unsigned short*)(ws + 1542144);
        unsigned short* xbf  = (unsigned short*)(ws + 2328576);

        hipMemsetAsync(ws, 0, 1542144, stream);
        hipMemsetAsync(out + 7225344, 0, 4, stream);

        cvt_x<<<7056, 256, 0, stream>>>(x, xbf);
        enc_gemm<<<dim3(24, 42), 256, 0, stream>>>(xbf, We, preact, rn2);
        act_jac<<<dim3(6, 256), 256, 0, stream>>>(preact, be, rn2, yenc, out + 7225344);
        dec_gemm<<<882, 256, 0, stream>>>(yenc, Wd, bd, out);
    }
}